// Round 2
// baseline (1148.847 us; speedup 1.0000x reference)
//
#include <hip/hip_runtime.h>

// Multiplexer: out[b, :] = full_input[b, idx[b]*64 : idx[b]*64+64]
// BATCH=262144, OUTPUT_DIM=64, NB_CTRL_SIG=16.
// Memory-bound gather: 16 threads/row, one float4 each (64 floats/row).
//
// idx is masked with &15: harness poison (0xAAAAAAAA) in indices during any
// transient launch would otherwise produce a wildly OOB read -> memory fault
// -> dead context -> all later launches silently no-op (the round-1 failure
// mode). For valid inputs (0..15) the mask is an identity.

#define OUT_DIM 64
#define ROWS_PER_BLOCK 16   // 256 threads / 16 threads-per-row

__global__ __launch_bounds__(256) void mux_kernel(const float* __restrict__ full_input,
                                                  const int* __restrict__ indices,
                                                  float* __restrict__ out,
                                                  int batch) {
    const int tid  = threadIdx.x;          // 0..255
    const int lane = tid & 15;             // which float4 within the row
    const int row  = blockIdx.x * ROWS_PER_BLOCK + (tid >> 4);
    if (row >= batch) return;

    const int idx = indices[row] & 15;     // mask: OOB-proof against poison
    // src: row*1024 + idx*64 floats, take float4 #lane
    const float4* src = reinterpret_cast<const float4*>(
        full_input + (size_t)row * (OUT_DIM * 16) + idx * OUT_DIM) + lane;
    float4* dst = reinterpret_cast<float4*>(out + (size_t)row * OUT_DIM) + lane;
    *dst = *src;
}

extern "C" void kernel_launch(void* const* d_in, const int* in_sizes, int n_in,
                              void* d_out, int out_size, void* d_ws, size_t ws_size,
                              hipStream_t stream) {
    const float* full_input = (const float*)d_in[0];
    const int*   indices    = (const int*)d_in[1];
    float*       out        = (float*)d_out;

    const int batch = in_sizes[1];                       // one index per row
    const int grid  = (batch + ROWS_PER_BLOCK - 1) / ROWS_PER_BLOCK;
    mux_kernel<<<grid, 256, 0, stream>>>(full_input, indices, out, batch);
}